// Round 7
// baseline (27.487 us; speedup 1.0000x reference)
//
#include <hip/hip_runtime.h>

#define BIN_MIN_F (-8.0f)
#define STEP_F (16.0f / 4095.0f)
#define INV_STEP (4095.0f / 16.0f)
#define LN2_F 0.69314718055994531f
#define VEC 8   // float4s per thread: 2048 blocks -> exactly 32 waves/CU, one round

typedef float f32x4 __attribute__((ext_vector_type(4)));

// v_log_f32 computes log2; inputs are in [1e-3, 1-1e-3] so no edge cases.
__device__ __forceinline__ float fast_logit(float x) {
    float l0 = __builtin_amdgcn_logf(x);         // log2(x)
    float l1 = __builtin_amdgcn_logf(1.0f - x);  // log2(1-x)
    return LN2_F * (l0 - l1);                    // ln(x/(1-x))
}

// Uniform-bin quantize: edge = floor((clamp(s)+8)*INV_STEP)*STEP - 8.
// scores in [-6.91, 6.91] so no upper clamp needed; fmax guards the floor.
__device__ __forceinline__ float quantize(float s) {
    float c = fmaxf(s, BIN_MIN_F);
    float t = floorf((c - BIN_MIN_F) * INV_STEP);
    return fmaf(t, STEP_F, BIN_MIN_F);
}

__device__ __forceinline__ f32x4 process4(f32x4 xv) {
    f32x4 r;
    #pragma unroll
    for (int j = 0; j < 4; ++j)
        r[j] = quantize(fast_logit(xv[j]));
    return r;
}

__global__ __launch_bounds__(256) void logodds_bins_kernel(
    const float* __restrict__ Xs,
    float* __restrict__ out,
    int n)
{
    const int n4 = n >> 2;
    const f32x4* __restrict__ in4 = reinterpret_cast<const f32x4*>(Xs);
    f32x4* __restrict__ out4      = reinterpret_cast<f32x4*>(out);

    const int base = blockIdx.x * (blockDim.x * VEC) + threadIdx.x;

    if (base + (VEC - 1) * 256 < n4) {
        // Fast path. A/B vs R6: loads are NONTEMPORAL (read-once stream,
        // don't allocate in L2/LLC -> leave cache bandwidth to the write
        // stream). Stores stay cached (nt-store regressed in R4).
        f32x4 v[VEC];
        #pragma unroll
        for (int k = 0; k < VEC; ++k)
            v[k] = __builtin_nontemporal_load(&in4[base + k * 256]);
        #pragma unroll
        for (int k = 0; k < VEC; ++k)
            out4[base + k * 256] = process4(v[k]);
    } else {
        // Ragged last block (not taken at N=16.7M, kept for generality).
        #pragma unroll
        for (int k = 0; k < VEC; ++k) {
            int i = base + k * 256;
            if (i < n4) out4[i] = process4(in4[i]);
        }
        // Scalar tail (N % 4)
        int tb = n4 << 2;
        for (int t = tb + (int)threadIdx.x; t < n; t += blockDim.x) {
            out[t] = quantize(fast_logit(Xs[t]));
        }
    }
}

extern "C" void kernel_launch(void* const* d_in, const int* in_sizes, int n_in,
                              void* d_out, int out_size, void* d_ws, size_t ws_size,
                              hipStream_t stream) {
    const float* Xs = (const float*)d_in[0];
    float* out      = (float*)d_out;
    const int n = in_sizes[0];

    const int block = 256;
    const int per_block = block * VEC;           // float4s per block (2048)
    int n4 = n >> 2;
    int grid = (n4 + per_block - 1) / per_block; // 2048 exactly @ N=16.7M
    if (grid < 1) grid = 1;

    logodds_bins_kernel<<<grid, block, 0, stream>>>(Xs, out, n);
}

// Round 8
// 25.153 us; speedup vs baseline: 1.0928x; 1.0928x over previous
//
#include <hip/hip_runtime.h>

#define BIN_MIN_F (-8.0f)
#define STEP_F (16.0f / 4095.0f)
#define INV_STEP (4095.0f / 16.0f)
#define LN2_F 0.69314718055994531f
#define VEC 8   // float4s per thread: 2048 blocks -> exactly 32 waves/CU, one round

typedef float f32x4 __attribute__((ext_vector_type(4)));

// v_log_f32 computes log2; inputs are in [1e-3, 1-1e-3] so no edge cases.
__device__ __forceinline__ float fast_logit(float x) {
    float l0 = __builtin_amdgcn_logf(x);         // log2(x)
    float l1 = __builtin_amdgcn_logf(1.0f - x);  // log2(1-x)
    return LN2_F * (l0 - l1);                    // ln(x/(1-x))
}

// Uniform-bin quantize: edge = floor((clamp(s)+8)*INV_STEP)*STEP - 8.
// scores in [-6.91, 6.91] so no upper clamp needed; fmax guards the floor.
__device__ __forceinline__ float quantize(float s) {
    float c = fmaxf(s, BIN_MIN_F);
    float t = floorf((c - BIN_MIN_F) * INV_STEP);
    return fmaf(t, STEP_F, BIN_MIN_F);
}

__device__ __forceinline__ f32x4 process4(f32x4 xv) {
    f32x4 r;
    #pragma unroll
    for (int j = 0; j < 4; ++j)
        r[j] = quantize(fast_logit(xv[j]));
    return r;
}

__global__ __launch_bounds__(256) void logodds_bins_kernel(
    const float* __restrict__ Xs,
    float* __restrict__ out,
    int n)
{
    const int n4 = n >> 2;
    const f32x4* __restrict__ in4 = reinterpret_cast<const f32x4*>(Xs);
    f32x4* __restrict__ out4      = reinterpret_cast<f32x4*>(out);

    const int base = blockIdx.x * (blockDim.x * VEC) + threadIdx.x;

    if (base + (VEC - 1) * 256 < n4) {
        // Fast path: full block, no guards. 8 independent 1KB wave-loads
        // issued before any compute. PLAIN cached loads AND stores:
        // nt-store regressed (R4, +1.5us), nt-load regressed (R7, +2.6us)
        // -> L2/LLC allocation helps this mixed streaming workload.
        f32x4 v[VEC];
        #pragma unroll
        for (int k = 0; k < VEC; ++k)
            v[k] = in4[base + k * 256];
        #pragma unroll
        for (int k = 0; k < VEC; ++k)
            out4[base + k * 256] = process4(v[k]);
    } else {
        // Ragged last block (not taken at N=16.7M, kept for generality).
        #pragma unroll
        for (int k = 0; k < VEC; ++k) {
            int i = base + k * 256;
            if (i < n4) out4[i] = process4(in4[i]);
        }
        // Scalar tail (N % 4)
        int tb = n4 << 2;
        for (int t = tb + (int)threadIdx.x; t < n; t += blockDim.x) {
            out[t] = quantize(fast_logit(Xs[t]));
        }
    }
}

extern "C" void kernel_launch(void* const* d_in, const int* in_sizes, int n_in,
                              void* d_out, int out_size, void* d_ws, size_t ws_size,
                              hipStream_t stream) {
    const float* Xs = (const float*)d_in[0];
    float* out      = (float*)d_out;
    const int n = in_sizes[0];

    const int block = 256;
    const int per_block = block * VEC;           // float4s per block (2048)
    int n4 = n >> 2;
    int grid = (n4 + per_block - 1) / per_block; // 2048 exactly @ N=16.7M
    if (grid < 1) grid = 1;

    logodds_bins_kernel<<<grid, block, 0, stream>>>(Xs, out, n);
}